// Round 16
// baseline (592.171 us; speedup 1.0000x reference)
//
#include <hip/hip_runtime.h>
#include <hip/hip_bf16.h>
#include <cstddef>

using bf16 = __hip_bfloat16;
typedef __bf16 bf16x8 __attribute__((ext_vector_type(8)));
typedef float f32x4 __attribute__((ext_vector_type(4)));

typedef __attribute__((address_space(1))) const void* gas1_t;
typedef __attribute__((address_space(3))) void* las3_t;

__device__ __forceinline__ void g2lds16(const void* g, void* l) {
  __builtin_amdgcn_global_load_lds((gas1_t)g, (las3_t)l, 16, 0, 0);
}

// ---------------------------------------------------------------- constants
#define M_ROWS 100352   // 32 * 56 * 56  (= 2048 windows * 49)

// ---------------------------------------------------------------- f32 -> bf16
__global__ void cvt_bf16(const float* __restrict__ in, bf16* __restrict__ out, int n) {
  int i = blockIdx.x * 256 + threadIdx.x;
  if (i < n) out[i] = __float2bfloat16(in[i]);
}

// ---------------------------------------------------------------- LN1 + shift + window partition
__global__ __launch_bounds__(256) void ln1_shift_kernel(
    const float* __restrict__ x, const float* __restrict__ w, const float* __restrict__ bb,
    bf16* __restrict__ hw) {
  int row = blockIdx.x * 4 + (threadIdx.x >> 6);
  int l = threadIdx.x & 63;
  int b_ = row / 49;
  int n  = row - b_ * 49;
  int bidx = b_ >> 6;
  int wi = b_ & 63;
  int wh = wi >> 3, ww = wi & 7;
  int r = n / 7, c = n - r * 7;
  int y = wh * 7 + r + 3;  if (y >= 56) y -= 56;
  int xx = ww * 7 + c + 3; if (xx >= 56) xx -= 56;
  size_t src = ((size_t)bidx * 3136 + (size_t)(y * 56 + xx)) * 256 + l * 4;
  float4 v = *reinterpret_cast<const float4*>(x + src);
  float s  = v.x + v.y + v.z + v.w;
  float ss = v.x * v.x + v.y * v.y + v.z * v.z + v.w * v.w;
#pragma unroll
  for (int off = 32; off > 0; off >>= 1) {
    s  += __shfl_xor(s, off);
    ss += __shfl_xor(ss, off);
  }
  float mean = s * (1.f / 256.f);
  float var  = ss * (1.f / 256.f) - mean * mean;
  float rs   = rsqrtf(var + 1e-5f);
  int ch = l * 4;
  float4 wv = *reinterpret_cast<const float4*>(w + ch);
  float4 bv = *reinterpret_cast<const float4*>(bb + ch);
  bf16 o[4];
  o[0] = __float2bfloat16((v.x - mean) * rs * wv.x + bv.x);
  o[1] = __float2bfloat16((v.y - mean) * rs * wv.y + bv.y);
  o[2] = __float2bfloat16((v.z - mean) * rs * wv.z + bv.z);
  o[3] = __float2bfloat16((v.w - mean) * rs * wv.w + bv.w);
  *reinterpret_cast<short4*>(hw + (size_t)row * 256 + ch) = *reinterpret_cast<const short4*>(o);
}

// ---------------------------------------------------------------- LN (identity mapping)
__global__ __launch_bounds__(256) void ln_kernel(
    const float* __restrict__ xin, const float* __restrict__ w, const float* __restrict__ bb,
    bf16* __restrict__ out) {
  int row = blockIdx.x * 4 + (threadIdx.x >> 6);
  int l = threadIdx.x & 63;
  size_t src = (size_t)row * 256 + l * 4;
  float4 v = *reinterpret_cast<const float4*>(xin + src);
  float s  = v.x + v.y + v.z + v.w;
  float ss = v.x * v.x + v.y * v.y + v.z * v.z + v.w * v.w;
#pragma unroll
  for (int off = 32; off > 0; off >>= 1) {
    s  += __shfl_xor(s, off);
    ss += __shfl_xor(ss, off);
  }
  float mean = s * (1.f / 256.f);
  float var  = ss * (1.f / 256.f) - mean * mean;
  float rs   = rsqrtf(var + 1e-5f);
  int ch = l * 4;
  float4 wv = *reinterpret_cast<const float4*>(w + ch);
  float4 bv = *reinterpret_cast<const float4*>(bb + ch);
  bf16 o[4];
  o[0] = __float2bfloat16((v.x - mean) * rs * wv.x + bv.x);
  o[1] = __float2bfloat16((v.y - mean) * rs * wv.y + bv.y);
  o[2] = __float2bfloat16((v.z - mean) * rs * wv.z + bv.z);
  o[3] = __float2bfloat16((v.w - mean) * rs * wv.w + bv.w);
  *reinterpret_cast<short4*>(out + src) = *reinterpret_cast<const short4*>(o);
}

// ---------------------------------------------------------------- MFMA attention (r6/r13, bf16)
__global__ __launch_bounds__(256) void attn_mfma_kernel(
    const bf16* __restrict__ qkv, const float* __restrict__ bias_table,
    bf16* __restrict__ attn_out) {
  __shared__ char smem[4 * 12992];
  const int tid = threadIdx.x;
  const int wid = tid >> 6;
  const int lane = tid & 63;
  const int lrow = lane & 15;
  const int kseg = lane >> 4;
  const int b_ = blockIdx.x >> 1;
  const int h = ((blockIdx.x & 1) << 2) + wid;
  const int wi = b_ & 63;
  const int wh = wi >> 3, ww = wi & 7;

  char* L = smem + wid * 12992;

  const bf16* src0 = qkv + (size_t)b_ * (49 * 768) + h * 32;
#pragma unroll
  for (int t = 0; t < 2; ++t) {
    const bf16* src = src0 + t * 256;
    char* dst = L + t * 4096;
#pragma unroll
    for (int it = 0; it < 4; ++it) {
      int c = it * 64 + lane;
      if (c < 196)
        g2lds16(src + (size_t)(c >> 2) * 768 + (((c & 3) ^ ((c >> 3) & 3)) * 8), dst + c * 16);
    }
  }
  {
    const bf16* src = src0 + 512;
    char* dst = L + 8192;
#pragma unroll
    for (int it = 0; it < 4; ++it) {
      int c = it * 64 + lane;
      if (c < 196)
        g2lds16(src + (size_t)(c >> 2) * 768 + (c & 3) * 8, dst + c * 16);
    }
  }
  if (lane < 60) {
    int4 z = {0, 0, 0, 0};
    *reinterpret_cast<int4*>(L + 8192 + (196 + lane) * 16) = z;
  }
  float* blds = reinterpret_cast<float*>(L + 12288);
  for (int e = lane; e < 169; e += 64) blds[e] = bias_table[e * 8 + h];

  asm volatile("s_waitcnt vmcnt(0) lgkmcnt(0)" ::: "memory");

  const int swb = (kseg ^ ((lrow >> 1) & 3)) * 16;
  bf16x8 qf[4], kf[4];
#pragma unroll
  for (int im = 0; im < 4; ++im)
    qf[im] = *reinterpret_cast<const bf16x8*>(L + (16 * im + lrow) * 64 + swb);
#pragma unroll
  for (int jn = 0; jn < 4; ++jn)
    kf[jn] = *reinterpret_cast<const bf16x8*>(L + 4096 + (16 * jn + lrow) * 64 + swb);
  f32x4 S[4][4] = {};
#pragma unroll
  for (int im = 0; im < 4; ++im)
#pragma unroll
    for (int jn = 0; jn < 4; ++jn)
      S[im][jn] = __builtin_amdgcn_mfma_f32_16x16x32_bf16(qf[im], kf[jn], S[im][jn], 0, 0, 0);

  const float scale = 0.17677669529663689f;
  int fj[4], rj[4], cj[4];
  bool jbad[4];
#pragma unroll
  for (int jn = 0; jn < 4; ++jn) {
    int j = 16 * jn + lrow;
    int rr = (j * 37) >> 8;
    int cc = j - rr * 7;
    rj[jn] = rr; cj[jn] = cc;
    int yj = wh * 7 + rr, xj = ww * 7 + cc;
    fj[jn] = (yj < 49 ? 0 : (yj < 53 ? 1 : 2)) * 3 + (xj < 49 ? 0 : (xj < 53 ? 1 : 2));
    jbad[jn] = (j >= 49);
  }
#pragma unroll
  for (int im = 0; im < 4; ++im) {
#pragma unroll
    for (int r = 0; r < 4; ++r) {
      int i = 16 * im + 4 * kseg + r;
      int ri = (i * 37) >> 8;
      int ci = i - ri * 7;
      int yi = wh * 7 + ri, xi = ww * 7 + ci;
      int fi = (yi < 49 ? 0 : (yi < 53 ? 1 : 2)) * 3 + (xi < 49 ? 0 : (xi < 53 ? 1 : 2));
#pragma unroll
      for (int jn = 0; jn < 4; ++jn) {
        float s = S[im][jn][r] * scale + blds[(ri - rj[jn] + 6) * 13 + (ci - cj[jn] + 6)];
        S[im][jn][r] = (fi != fj[jn] || jbad[jn]) ? -1e30f : s;
      }
    }
  }

#pragma unroll
  for (int im = 0; im < 4; ++im) {
#pragma unroll
    for (int r = 0; r < 4; ++r) {
      float m = fmaxf(fmaxf(S[im][0][r], S[im][1][r]), fmaxf(S[im][2][r], S[im][3][r]));
      m = fmaxf(m, __shfl_xor(m, 1));
      m = fmaxf(m, __shfl_xor(m, 2));
      m = fmaxf(m, __shfl_xor(m, 4));
      m = fmaxf(m, __shfl_xor(m, 8));
      float e0 = __expf(S[im][0][r] - m);
      float e1 = __expf(S[im][1][r] - m);
      float e2 = __expf(S[im][2][r] - m);
      float e3 = __expf(S[im][3][r] - m);
      float sum = e0 + e1 + e2 + e3;
      sum += __shfl_xor(sum, 1);
      sum += __shfl_xor(sum, 2);
      sum += __shfl_xor(sum, 4);
      sum += __shfl_xor(sum, 8);
      float inv = 1.f / sum;
      int i = 16 * im + 4 * kseg + r;
      int xorv = (i & 7) << 4;
      float ev[4] = {e0, e1, e2, e3};
#pragma unroll
      for (int jn = 0; jn < 4; ++jn) {
        bf16 pb = __float2bfloat16(ev[jn] * inv);
        *reinterpret_cast<unsigned short*>(L + i * 128 + (((16 * jn + lrow) * 2) ^ xorv)) =
            *reinterpret_cast<unsigned short*>(&pb);
      }
    }
  }

  f32x4 O[4][2] = {};
#pragma unroll
  for (int ks = 0; ks < 2; ++ks) {
    bf16x8 pa[4];
#pragma unroll
    for (int im = 0; im < 4; ++im) {
      int row = 16 * im + lrow;
      int byte = (ks * 64 + kseg * 16) ^ ((row & 7) << 4);
      pa[im] = *reinterpret_cast<const bf16x8*>(L + row * 128 + byte);
    }
#pragma unroll
    for (int dn = 0; dn < 2; ++dn) {
      bf16x8 vf;
#pragma unroll
      for (int jj = 0; jj < 8; ++jj) {
        int j = ks * 32 + kseg * 8 + jj;
        reinterpret_cast<unsigned short*>(&vf)[jj] =
            *reinterpret_cast<const unsigned short*>(L + 8192 + j * 64 + (16 * dn + lrow) * 2);
      }
#pragma unroll
      for (int im = 0; im < 4; ++im)
        O[im][dn] = __builtin_amdgcn_mfma_f32_16x16x32_bf16(pa[im], vf, O[im][dn], 0, 0, 0);
    }
  }

  bf16* outb = attn_out + (size_t)b_ * 49 * 256 + h * 32;
#pragma unroll
  for (int im = 0; im < 4; ++im) {
#pragma unroll
    for (int r = 0; r < 4; ++r) {
      int i = 16 * im + 4 * kseg + r;
      if (i < 49) {
#pragma unroll
        for (int dn = 0; dn < 2; ++dn)
          outb[(size_t)i * 256 + 16 * dn + lrow] = __float2bfloat16(O[im][dn][r]);
      }
    }
  }
}

enum { EPI_BF16 = 0, EPI_GELU = 1, EPI_PROJ = 2, EPI_ADD = 3 };

__device__ __forceinline__ void epi_store(int EPI, int m, int nch, int N, float val,
                                          void* outp, const float* addf) {
  if (EPI == EPI_BF16) {
    ((bf16*)outp)[(size_t)m * N + nch] = __float2bfloat16(val);
  } else if (EPI == EPI_GELU) {
    float u = val;
    float yv = 0.7978845608028654f * (u + 0.044715f * u * u * u);
    float e = __expf(2.f * yv);
    float th = 1.f - 2.f / (e + 1.f);
    val = 0.5f * u * (1.f + th);
    ((bf16*)outp)[(size_t)m * N + nch] = __float2bfloat16(val);
  } else if (EPI == EPI_PROJ) {
    int b_ = m / 49;
    int n = m - b_ * 49;
    int bidx = b_ >> 6;
    int wi = b_ & 63;
    int wh2 = wi >> 3, ww2 = wi & 7;
    int rr = n / 7, cc = n - rr * 7;
    int y = wh2 * 7 + rr + 3;  if (y >= 56) y -= 56;
    int xx = ww2 * 7 + cc + 3; if (xx >= 56) xx -= 56;
    int td = bidx * 3136 + y * 56 + xx;
    size_t o = (size_t)td * 256 + nch;
    ((float*)outp)[o] = addf[o] + val;
  } else {  // EPI_ADD
    size_t o = (size_t)m * N + nch;
    ((float*)outp)[o] = addf[o] + val;
  }
}

// ---------------------------------------------------------------- GEMM 128x256 (M x N), 8 waves
// r13 components (static-K unroll, slot-XOR swizzle, g2lds16, counted vmcnt,
// XCD grid swizzle) with a wide-N tile: NY halves/quarters -> staged bytes
// fc2 820->410MB, fc1 820->616, qkv 616->462, proj 205->154. acc stays [4][4]
// (64 AGPR) so the <=128-reg bucket holds: 4 waves/SIMD -> 2 blocks/CU
// (16 waves/CU vs r13's ~11). LDS 48KB (not binding).
template <int EPI, int K>
__global__ __launch_bounds__(512, 4) void gemm_kernel(
    const bf16* __restrict__ A, const bf16* __restrict__ Bw,
    const float* __restrict__ bias, int NY, int N,
    void* __restrict__ outp, const float* __restrict__ addf) {
  __shared__ __align__(16) bf16 As[2][128][32];   // 16 KB
  __shared__ __align__(16) bf16 Bs[2][256][32];   // 32 KB

  const int tid = threadIdx.x;
  const int bid = blockIdx.x;
  const int nblk = gridDim.x;
  const int w = (bid & 7) * (nblk >> 3) + (bid >> 3);
  const int bx = w / NY;
  const int by = w - bx * NY;
  const int m0 = bx * 128;
  const int n0 = by * 256;

  const int wv = tid >> 6;        // 0..7
  const int wm = wv >> 2;         // 0..1  (64-row halves)
  const int wn = wv & 3;          // 0..3  (64-col quarters)
  const int l = tid & 63;
  const int lrow = l & 15;
  const int kseg = l >> 4;
  const int sw = (kseg ^ ((lrow >> 1) & 3)) * 8;

  // staging (3 g2lds16/thread/tile): A unit = tid (512), B units = tid, 512+tid (1024)
  const int ra = tid >> 2, sa = tid & 3;
  const int ca = (sa ^ ((ra >> 1) & 3)) * 8;
  const bf16* gA  = A  + (size_t)(m0 + ra) * K + ca;
  char* lA  = (char*)(&As[0][0][0]) + tid * 16;          // + buf*8192
  const bf16* gB0 = Bw + (size_t)(n0 + ra) * K + ca;     // B rows 0..127
  char* lB0 = (char*)(&Bs[0][0][0]) + tid * 16;          // + buf*16384
  const int u1 = 512 + tid;
  const int rb1 = u1 >> 2, sb1 = u1 & 3;
  const int cb1 = (sb1 ^ ((rb1 >> 1) & 3)) * 8;
  const bf16* gB1 = Bw + (size_t)(n0 + rb1) * K + cb1;   // B rows 128..255
  char* lB1 = (char*)(&Bs[0][0][0]) + u1 * 16;

  f32x4 acc[4][4] = {};
  constexpr int nk = K >> 5;

  g2lds16(gA, lA);  g2lds16(gB0, lB0);  g2lds16(gB1, lB1);

#pragma unroll
  for (int kt = 0; kt < nk; ++kt) {
    const int buf = kt & 1;
    if (kt + 1 < nk) {
      const int pb = buf ^ 1;
      g2lds16(gA  + (kt + 1) * 32, lA  + pb * 8192);
      g2lds16(gB0 + (kt + 1) * 32, lB0 + pb * 16384);
      g2lds16(gB1 + (kt + 1) * 32, lB1 + pb * 16384);
      asm volatile("s_waitcnt vmcnt(3)" ::: "memory");   // tile kt resident
    } else {
      asm volatile("s_waitcnt vmcnt(0)" ::: "memory");
    }
    __builtin_amdgcn_s_barrier();
    asm volatile("" ::: "memory");

    bf16x8 bfr[4];
#pragma unroll
    for (int in_ = 0; in_ < 4; ++in_)
      bfr[in_] = *reinterpret_cast<const bf16x8*>(&Bs[buf][wn * 64 + in_ * 16 + lrow][sw]);
#pragma unroll
    for (int im = 0; im < 4; ++im) {
      bf16x8 af = *reinterpret_cast<const bf16x8*>(&As[buf][wm * 64 + im * 16 + lrow][sw]);
#pragma unroll
      for (int in_ = 0; in_ < 4; ++in_)
        acc[im][in_] = __builtin_amdgcn_mfma_f32_16x16x32_bf16(af, bfr[in_], acc[im][in_], 0, 0, 0);
    }

    asm volatile("" ::: "memory");
    __builtin_amdgcn_s_barrier();   // reads of buf done; safe to overwrite next iter
  }

#pragma unroll
  for (int im = 0; im < 4; ++im) {
#pragma unroll
    for (int r = 0; r < 4; ++r) {
      int m = m0 + wm * 64 + im * 16 + kseg * 4 + r;
#pragma unroll
      for (int in_ = 0; in_ < 4; ++in_) {
        int nch = n0 + wn * 64 + in_ * 16 + lrow;
        epi_store(EPI, m, nch, N, acc[im][in_][r] + bias[nch], outp, addf);
      }
    }
  }
}

// ---------------------------------------------------------------- launch
extern "C" void kernel_launch(void* const* d_in, const int* in_sizes, int n_in,
                              void* d_out, int out_size, void* d_ws, size_t ws_size,
                              hipStream_t stream) {
  const float* x      = (const float*)d_in[0];
  const float* n1w    = (const float*)d_in[1];
  const float* n1b    = (const float*)d_in[2];
  const float* qkv_w  = (const float*)d_in[3];
  const float* qkv_b  = (const float*)d_in[4];
  const float* proj_w = (const float*)d_in[5];
  const float* proj_b = (const float*)d_in[6];
  const float* relb   = (const float*)d_in[7];
  const float* n2w    = (const float*)d_in[8];
  const float* n2b    = (const float*)d_in[9];
  const float* fc1_w  = (const float*)d_in[10];
  const float* fc1_b  = (const float*)d_in[11];
  const float* fc2_w  = (const float*)d_in[12];
  const float* fc2_b  = (const float*)d_in[13];
  float* out = (float*)d_out;
  char* ws = (char*)d_ws;

  const size_t HW_BYTES  = (size_t)M_ROWS * 256 * 2;
  const size_t QKV_BYTES = (size_t)M_ROWS * 768 * 2;
  const size_t YIN_BYTES = (size_t)M_ROWS * 256 * 2;

  char* regA = ws;
  bf16* hw    = (bf16*)regA;                // LN1 out / attn_out
  bf16* qkvb  = (bf16*)(regA + HW_BYTES);   // qkv
  bf16* h1    = (bf16*)regA;                // fc1 out (region A reuse, 205.5 MB)
  char* p = regA + HW_BYTES + QKV_BYTES;
  bf16* y_in = (bf16*)p;                 p += YIN_BYTES;
  bf16* wq   = (bf16*)p;                 p += (size_t)768 * 256 * 2;
  bf16* wp   = (bf16*)p;                 p += (size_t)256 * 256 * 2;
  bf16* wf1  = (bf16*)p;                 p += (size_t)1024 * 256 * 2;
  bf16* wf2  = (bf16*)p;                 p += (size_t)256 * 1024 * 2;
  float* x_new = out;                    // post-attn residual, fp32, in d_out
  (void)ws_size; (void)in_sizes; (void)n_in; (void)out_size;

  cvt_bf16<<<768, 256, 0, stream>>>(qkv_w, wq, 768 * 256);
  cvt_bf16<<<256, 256, 0, stream>>>(proj_w, wp, 256 * 256);
  cvt_bf16<<<1024, 256, 0, stream>>>(fc1_w, wf1, 1024 * 256);
  cvt_bf16<<<1024, 256, 0, stream>>>(fc2_w, wf2, 256 * 1024);

  ln1_shift_kernel<<<M_ROWS / 4, 256, 0, stream>>>(x, n1w, n1b, hw);

  // qkv: (100352,256)@(768,256)^T   grid 784*3 = 2352, tile 128x256
  gemm_kernel<EPI_BF16, 256><<<784 * 3, 512, 0, stream>>>(hw, wq, qkv_b, 3, 768, qkvb, nullptr);

  attn_mfma_kernel<<<4096, 256, 0, stream>>>(qkvb, relb, hw);

  // proj: (100352,256)@(256,256)^T  grid 784 (NY=1 -> A staged exactly once)
  gemm_kernel<EPI_PROJ, 256><<<784, 512, 0, stream>>>(hw, wp, proj_b, 1, 256, x_new, x);

  ln_kernel<<<M_ROWS / 4, 256, 0, stream>>>(x_new, n2w, n2b, y_in);

  // fc1: (100352,256)@(1024,256)^T  grid 784*4 = 3136
  gemm_kernel<EPI_GELU, 256><<<784 * 4, 512, 0, stream>>>(y_in, wf1, fc1_b, 4, 1024, h1, nullptr);

  // fc2: (100352,1024)@(256,1024)^T grid 784 (NY=1, staged bytes halved)
  gemm_kernel<EPI_ADD, 1024><<<784, 512, 0, stream>>>(h1, wf2, fc2_b, 1, 256, out, x_new);
}

// Round 18
// 539.212 us; speedup vs baseline: 1.0982x; 1.0982x over previous
//
#include <hip/hip_runtime.h>
#include <hip/hip_bf16.h>
#include <cstddef>

using bf16 = __hip_bfloat16;
typedef __bf16 bf16x8 __attribute__((ext_vector_type(8)));
typedef float f32x4 __attribute__((ext_vector_type(4)));

typedef __attribute__((address_space(1))) const void* gas1_t;
typedef __attribute__((address_space(3))) void* las3_t;

__device__ __forceinline__ void g2lds16(const void* g, void* l) {
  __builtin_amdgcn_global_load_lds((gas1_t)g, (las3_t)l, 16, 0, 0);
}

// ---------------------------------------------------------------- constants
#define M_ROWS 100352   // 32 * 56 * 56  (= 2048 windows * 49)

// ---------------------------------------------------------------- f32 -> bf16
__global__ void cvt_bf16(const float* __restrict__ in, bf16* __restrict__ out, int n) {
  int i = blockIdx.x * 256 + threadIdx.x;
  if (i < n) out[i] = __float2bfloat16(in[i]);
}

// ---------------------------------------------------------------- LN1 + shift + window partition
__global__ __launch_bounds__(256) void ln1_shift_kernel(
    const float* __restrict__ x, const float* __restrict__ w, const float* __restrict__ bb,
    bf16* __restrict__ hw) {
  int row = blockIdx.x * 4 + (threadIdx.x >> 6);
  int l = threadIdx.x & 63;
  int b_ = row / 49;
  int n  = row - b_ * 49;
  int bidx = b_ >> 6;
  int wi = b_ & 63;
  int wh = wi >> 3, ww = wi & 7;
  int r = n / 7, c = n - r * 7;
  int y = wh * 7 + r + 3;  if (y >= 56) y -= 56;
  int xx = ww * 7 + c + 3; if (xx >= 56) xx -= 56;
  size_t src = ((size_t)bidx * 3136 + (size_t)(y * 56 + xx)) * 256 + l * 4;
  float4 v = *reinterpret_cast<const float4*>(x + src);
  float s  = v.x + v.y + v.z + v.w;
  float ss = v.x * v.x + v.y * v.y + v.z * v.z + v.w * v.w;
#pragma unroll
  for (int off = 32; off > 0; off >>= 1) {
    s  += __shfl_xor(s, off);
    ss += __shfl_xor(ss, off);
  }
  float mean = s * (1.f / 256.f);
  float var  = ss * (1.f / 256.f) - mean * mean;
  float rs   = rsqrtf(var + 1e-5f);
  int ch = l * 4;
  float4 wv = *reinterpret_cast<const float4*>(w + ch);
  float4 bv = *reinterpret_cast<const float4*>(bb + ch);
  bf16 o[4];
  o[0] = __float2bfloat16((v.x - mean) * rs * wv.x + bv.x);
  o[1] = __float2bfloat16((v.y - mean) * rs * wv.y + bv.y);
  o[2] = __float2bfloat16((v.z - mean) * rs * wv.z + bv.z);
  o[3] = __float2bfloat16((v.w - mean) * rs * wv.w + bv.w);
  *reinterpret_cast<short4*>(hw + (size_t)row * 256 + ch) = *reinterpret_cast<const short4*>(o);
}

// ---------------------------------------------------------------- LN (identity mapping)
__global__ __launch_bounds__(256) void ln_kernel(
    const float* __restrict__ xin, const float* __restrict__ w, const float* __restrict__ bb,
    bf16* __restrict__ out) {
  int row = blockIdx.x * 4 + (threadIdx.x >> 6);
  int l = threadIdx.x & 63;
  size_t src = (size_t)row * 256 + l * 4;
  float4 v = *reinterpret_cast<const float4*>(xin + src);
  float s  = v.x + v.y + v.z + v.w;
  float ss = v.x * v.x + v.y * v.y + v.z * v.z + v.w * v.w;
#pragma unroll
  for (int off = 32; off > 0; off >>= 1) {
    s  += __shfl_xor(s, off);
    ss += __shfl_xor(ss, off);
  }
  float mean = s * (1.f / 256.f);
  float var  = ss * (1.f / 256.f) - mean * mean;
  float rs   = rsqrtf(var + 1e-5f);
  int ch = l * 4;
  float4 wv = *reinterpret_cast<const float4*>(w + ch);
  float4 bv = *reinterpret_cast<const float4*>(bb + ch);
  bf16 o[4];
  o[0] = __float2bfloat16((v.x - mean) * rs * wv.x + bv.x);
  o[1] = __float2bfloat16((v.y - mean) * rs * wv.y + bv.y);
  o[2] = __float2bfloat16((v.z - mean) * rs * wv.z + bv.z);
  o[3] = __float2bfloat16((v.w - mean) * rs * wv.w + bv.w);
  *reinterpret_cast<short4*>(out + src) = *reinterpret_cast<const short4*>(o);
}

// ---------------------------------------------------------------- MFMA attention (r6, verified)
__global__ __launch_bounds__(256) void attn_mfma_kernel(
    const bf16* __restrict__ qkv, const float* __restrict__ bias_table,
    bf16* __restrict__ attn_out) {
  __shared__ char smem[4 * 12992];
  const int tid = threadIdx.x;
  const int wid = tid >> 6;
  const int lane = tid & 63;
  const int lrow = lane & 15;
  const int kseg = lane >> 4;
  const int b_ = blockIdx.x >> 1;
  const int h = ((blockIdx.x & 1) << 2) + wid;
  const int wi = b_ & 63;
  const int wh = wi >> 3, ww = wi & 7;

  char* L = smem + wid * 12992;

  const bf16* src0 = qkv + (size_t)b_ * (49 * 768) + h * 32;
#pragma unroll
  for (int t = 0; t < 2; ++t) {
    const bf16* src = src0 + t * 256;
    char* dst = L + t * 4096;
#pragma unroll
    for (int it = 0; it < 4; ++it) {
      int c = it * 64 + lane;
      if (c < 196)
        g2lds16(src + (size_t)(c >> 2) * 768 + (((c & 3) ^ ((c >> 3) & 3)) * 8), dst + c * 16);
    }
  }
  {
    const bf16* src = src0 + 512;
    char* dst = L + 8192;
#pragma unroll
    for (int it = 0; it < 4; ++it) {
      int c = it * 64 + lane;
      if (c < 196)
        g2lds16(src + (size_t)(c >> 2) * 768 + (c & 3) * 8, dst + c * 16);
    }
  }
  if (lane < 60) {
    int4 z = {0, 0, 0, 0};
    *reinterpret_cast<int4*>(L + 8192 + (196 + lane) * 16) = z;
  }
  float* blds = reinterpret_cast<float*>(L + 12288);
  for (int e = lane; e < 169; e += 64) blds[e] = bias_table[e * 8 + h];

  asm volatile("s_waitcnt vmcnt(0) lgkmcnt(0)" ::: "memory");

  const int swb = (kseg ^ ((lrow >> 1) & 3)) * 16;
  bf16x8 qf[4], kf[4];
#pragma unroll
  for (int im = 0; im < 4; ++im)
    qf[im] = *reinterpret_cast<const bf16x8*>(L + (16 * im + lrow) * 64 + swb);
#pragma unroll
  for (int jn = 0; jn < 4; ++jn)
    kf[jn] = *reinterpret_cast<const bf16x8*>(L + 4096 + (16 * jn + lrow) * 64 + swb);
  f32x4 S[4][4] = {};
#pragma unroll
  for (int im = 0; im < 4; ++im)
#pragma unroll
    for (int jn = 0; jn < 4; ++jn)
      S[im][jn] = __builtin_amdgcn_mfma_f32_16x16x32_bf16(qf[im], kf[jn], S[im][jn], 0, 0, 0);

  const float scale = 0.17677669529663689f;
  int fj[4], rj[4], cj[4];
  bool jbad[4];
#pragma unroll
  for (int jn = 0; jn < 4; ++jn) {
    int j = 16 * jn + lrow;
    int rr = (j * 37) >> 8;
    int cc = j - rr * 7;
    rj[jn] = rr; cj[jn] = cc;
    int yj = wh * 7 + rr, xj = ww * 7 + cc;
    fj[jn] = (yj < 49 ? 0 : (yj < 53 ? 1 : 2)) * 3 + (xj < 49 ? 0 : (xj < 53 ? 1 : 2));
    jbad[jn] = (j >= 49);
  }
#pragma unroll
  for (int im = 0; im < 4; ++im) {
#pragma unroll
    for (int r = 0; r < 4; ++r) {
      int i = 16 * im + 4 * kseg + r;
      int ri = (i * 37) >> 8;
      int ci = i - ri * 7;
      int yi = wh * 7 + ri, xi = ww * 7 + ci;
      int fi = (yi < 49 ? 0 : (yi < 53 ? 1 : 2)) * 3 + (xi < 49 ? 0 : (xi < 53 ? 1 : 2));
#pragma unroll
      for (int jn = 0; jn < 4; ++jn) {
        float s = S[im][jn][r] * scale + blds[(ri - rj[jn] + 6) * 13 + (ci - cj[jn] + 6)];
        S[im][jn][r] = (fi != fj[jn] || jbad[jn]) ? -1e30f : s;
      }
    }
  }

#pragma unroll
  for (int im = 0; im < 4; ++im) {
#pragma unroll
    for (int r = 0; r < 4; ++r) {
      float m = fmaxf(fmaxf(S[im][0][r], S[im][1][r]), fmaxf(S[im][2][r], S[im][3][r]));
      m = fmaxf(m, __shfl_xor(m, 1));
      m = fmaxf(m, __shfl_xor(m, 2));
      m = fmaxf(m, __shfl_xor(m, 4));
      m = fmaxf(m, __shfl_xor(m, 8));
      float e0 = __expf(S[im][0][r] - m);
      float e1 = __expf(S[im][1][r] - m);
      float e2 = __expf(S[im][2][r] - m);
      float e3 = __expf(S[im][3][r] - m);
      float sum = e0 + e1 + e2 + e3;
      sum += __shfl_xor(sum, 1);
      sum += __shfl_xor(sum, 2);
      sum += __shfl_xor(sum, 4);
      sum += __shfl_xor(sum, 8);
      float inv = 1.f / sum;
      int i = 16 * im + 4 * kseg + r;
      int xorv = (i & 7) << 4;
      float ev[4] = {e0, e1, e2, e3};
#pragma unroll
      for (int jn = 0; jn < 4; ++jn) {
        bf16 pb = __float2bfloat16(ev[jn] * inv);
        *reinterpret_cast<unsigned short*>(L + i * 128 + (((16 * jn + lrow) * 2) ^ xorv)) =
            *reinterpret_cast<unsigned short*>(&pb);
      }
    }
  }

  f32x4 O[4][2] = {};
#pragma unroll
  for (int ks = 0; ks < 2; ++ks) {
    bf16x8 pa[4];
#pragma unroll
    for (int im = 0; im < 4; ++im) {
      int row = 16 * im + lrow;
      int byte = (ks * 64 + kseg * 16) ^ ((row & 7) << 4);
      pa[im] = *reinterpret_cast<const bf16x8*>(L + row * 128 + byte);
    }
#pragma unroll
    for (int dn = 0; dn < 2; ++dn) {
      bf16x8 vf;
#pragma unroll
      for (int jj = 0; jj < 8; ++jj) {
        int j = ks * 32 + kseg * 8 + jj;
        reinterpret_cast<unsigned short*>(&vf)[jj] =
            *reinterpret_cast<const unsigned short*>(L + 8192 + j * 64 + (16 * dn + lrow) * 2);
      }
#pragma unroll
      for (int im = 0; im < 4; ++im)
        O[im][dn] = __builtin_amdgcn_mfma_f32_16x16x32_bf16(pa[im], vf, O[im][dn], 0, 0, 0);
    }
  }

  bf16* outb = attn_out + (size_t)b_ * 49 * 256 + h * 32;
#pragma unroll
  for (int im = 0; im < 4; ++im) {
#pragma unroll
    for (int r = 0; r < 4; ++r) {
      int i = 16 * im + 4 * kseg + r;
      if (i < 49) {
#pragma unroll
        for (int dn = 0; dn < 2; ++dn)
          outb[(size_t)i * 256 + 16 * dn + lrow] = __float2bfloat16(O[im][dn][r]);
      }
    }
  }
}

enum { EPI_BF16 = 0, EPI_GELU = 1, EPI_PROJ = 2, EPI_ADD = 3 };

__device__ __forceinline__ void epi_store(int EPI, int m, int nch, int N, float val,
                                          void* outp, const float* addf) {
  if (EPI == EPI_BF16) {
    ((bf16*)outp)[(size_t)m * N + nch] = __float2bfloat16(val);
  } else if (EPI == EPI_GELU) {
    float u = val;
    float yv = 0.7978845608028654f * (u + 0.044715f * u * u * u);
    float e = __expf(2.f * yv);
    float th = 1.f - 2.f / (e + 1.f);
    val = 0.5f * u * (1.f + th);
    ((bf16*)outp)[(size_t)m * N + nch] = __float2bfloat16(val);
  } else if (EPI == EPI_PROJ) {
    int b_ = m / 49;
    int n = m - b_ * 49;
    int bidx = b_ >> 6;
    int wi = b_ & 63;
    int wh2 = wi >> 3, ww2 = wi & 7;
    int rr = n / 7, cc = n - rr * 7;
    int y = wh2 * 7 + rr + 3;  if (y >= 56) y -= 56;
    int xx = ww2 * 7 + cc + 3; if (xx >= 56) xx -= 56;
    int td = bidx * 3136 + y * 56 + xx;
    size_t o = (size_t)td * 256 + nch;
    ((float*)outp)[o] = addf[o] + val;
  } else {  // EPI_ADD
    size_t o = (size_t)m * N + nch;
    ((float*)outp)[o] = addf[o] + val;
  }
}

// ---------------------------------------------------------------- GEMM 128x128 (r13: best verified)
// 4-wave blocks (barrier-convoy sweet spot), static-K full unroll (VALU 6%),
// 2-buffer depth-1 prefetch + counted vmcnt(4/0), zero-conflict slot-XOR
// swizzle, XCD-swizzled grid, __launch_bounds__(256,4). Runs at the measured
// structural staging wall (~5.7 TB/s; duration = staged_bytes / 5.7).
template <int EPI, int K>
__global__ __launch_bounds__(256, 4) void gemm_kernel(
    const bf16* __restrict__ A, const bf16* __restrict__ Bw,
    const float* __restrict__ bias, int NY, int N,
    void* __restrict__ outp, const float* __restrict__ addf) {
  __shared__ __align__(16) bf16 As[2][128][32];
  __shared__ __align__(16) bf16 Bs[2][128][32];

  const int tid = threadIdx.x;
  const int bid = blockIdx.x;
  const int nblk = gridDim.x;
  const int w = (bid & 7) * (nblk >> 3) + (bid >> 3);
  const int bx = w / NY;
  const int by = w - bx * NY;
  const int m0 = bx * 128;
  const int n0 = by * 128;

  const int wv = tid >> 6;
  const int wm = wv >> 1, wn = wv & 1;
  const int l = tid & 63;
  const int lrow = l & 15;
  const int kseg = l >> 4;
  const int sw = (kseg ^ ((lrow >> 1) & 3)) * 8;

  const int idx0 = tid, idx1 = 256 + tid;
  const int r0 = idx0 >> 2, c0 = ((idx0 & 3) ^ ((idx0 >> 3) & 3)) * 8;
  const int r1 = idx1 >> 2, c1 = ((idx1 & 3) ^ ((idx1 >> 3) & 3)) * 8;
  const bf16* ga0 = A  + (size_t)(m0 + r0) * K + c0;
  const bf16* ga1 = A  + (size_t)(m0 + r1) * K + c1;
  const bf16* gb0 = Bw + (size_t)(n0 + r0) * K + c0;
  const bf16* gb1 = Bw + (size_t)(n0 + r1) * K + c1;
  char* la0 = (char*)(&As[0][0][0]) + idx0 * 16;   // +buf*8192
  char* la1 = (char*)(&As[0][0][0]) + idx1 * 16;
  char* lb0 = (char*)(&Bs[0][0][0]) + idx0 * 16;
  char* lb1 = (char*)(&Bs[0][0][0]) + idx1 * 16;

  f32x4 acc[4][4] = {};
  constexpr int nk = K >> 5;

  g2lds16(ga0, la0);  g2lds16(ga1, la1);
  g2lds16(gb0, lb0);  g2lds16(gb1, lb1);

#pragma unroll
  for (int kt = 0; kt < nk; ++kt) {
    const int buf = kt & 1;
    if (kt + 1 < nk) {
      const int pb = buf ^ 1;
      g2lds16(ga0 + (kt + 1) * 32, la0 + pb * 8192);
      g2lds16(ga1 + (kt + 1) * 32, la1 + pb * 8192);
      g2lds16(gb0 + (kt + 1) * 32, lb0 + pb * 8192);
      g2lds16(gb1 + (kt + 1) * 32, lb1 + pb * 8192);
      asm volatile("s_waitcnt vmcnt(4)" ::: "memory");   // tile kt resident
    } else {
      asm volatile("s_waitcnt vmcnt(0)" ::: "memory");
    }
    __builtin_amdgcn_s_barrier();
    asm volatile("" ::: "memory");

    bf16x8 bfr[4];
#pragma unroll
    for (int in_ = 0; in_ < 4; ++in_)
      bfr[in_] = *reinterpret_cast<const bf16x8*>(&Bs[buf][wn * 64 + in_ * 16 + lrow][sw]);
#pragma unroll
    for (int im = 0; im < 4; ++im) {
      bf16x8 af = *reinterpret_cast<const bf16x8*>(&As[buf][wm * 64 + im * 16 + lrow][sw]);
#pragma unroll
      for (int in_ = 0; in_ < 4; ++in_)
        acc[im][in_] = __builtin_amdgcn_mfma_f32_16x16x32_bf16(af, bfr[in_], acc[im][in_], 0, 0, 0);
    }

    asm volatile("" ::: "memory");
    __builtin_amdgcn_s_barrier();
  }

#pragma unroll
  for (int im = 0; im < 4; ++im) {
#pragma unroll
    for (int r = 0; r < 4; ++r) {
      int m = m0 + wm * 64 + im * 16 + kseg * 4 + r;
#pragma unroll
      for (int in_ = 0; in_ < 4; ++in_) {
        int nch = n0 + wn * 64 + in_ * 16 + lrow;
        epi_store(EPI, m, nch, N, acc[im][in_][r] + bias[nch], outp, addf);
      }
    }
  }
}

// ---------------------------------------------------------------- launch
extern "C" void kernel_launch(void* const* d_in, const int* in_sizes, int n_in,
                              void* d_out, int out_size, void* d_ws, size_t ws_size,
                              hipStream_t stream) {
  const float* x      = (const float*)d_in[0];
  const float* n1w    = (const float*)d_in[1];
  const float* n1b    = (const float*)d_in[2];
  const float* qkv_w  = (const float*)d_in[3];
  const float* qkv_b  = (const float*)d_in[4];
  const float* proj_w = (const float*)d_in[5];
  const float* proj_b = (const float*)d_in[6];
  const float* relb   = (const float*)d_in[7];
  const float* n2w    = (const float*)d_in[8];
  const float* n2b    = (const float*)d_in[9];
  const float* fc1_w  = (const float*)d_in[10];
  const float* fc1_b  = (const float*)d_in[11];
  const float* fc2_w  = (const float*)d_in[12];
  const float* fc2_b  = (const float*)d_in[13];
  float* out = (float*)d_out;
  char* ws = (char*)d_ws;

  const size_t HW_BYTES  = (size_t)M_ROWS * 256 * 2;
  const size_t QKV_BYTES = (size_t)M_ROWS * 768 * 2;
  const size_t YIN_BYTES = (size_t)M_ROWS * 256 * 2;

  char* regA = ws;
  bf16* hw    = (bf16*)regA;
  bf16* qkvb  = (bf16*)(regA + HW_BYTES);
  bf16* h1    = (bf16*)regA;
  char* p = regA + HW_BYTES + QKV_BYTES;
  bf16* y_in = (bf16*)p;                 p += YIN_BYTES;
  bf16* wq   = (bf16*)p;                 p += (size_t)768 * 256 * 2;
  bf16* wp   = (bf16*)p;                 p += (size_t)256 * 256 * 2;
  bf16* wf1  = (bf16*)p;                 p += (size_t)1024 * 256 * 2;
  bf16* wf2  = (bf16*)p;                 p += (size_t)256 * 1024 * 2;
  float* x_new = out;                    // post-attn residual, fp32, in d_out
  (void)ws_size; (void)in_sizes; (void)n_in; (void)out_size;

  cvt_bf16<<<768, 256, 0, stream>>>(qkv_w, wq, 768 * 256);
  cvt_bf16<<<256, 256, 0, stream>>>(proj_w, wp, 256 * 256);
  cvt_bf16<<<1024, 256, 0, stream>>>(fc1_w, wf1, 1024 * 256);
  cvt_bf16<<<1024, 256, 0, stream>>>(fc2_w, wf2, 256 * 1024);

  ln1_shift_kernel<<<M_ROWS / 4, 256, 0, stream>>>(x, n1w, n1b, hw);

  // qkv: (100352,256)@(768,256)^T   grid 784*6 = 4704
  gemm_kernel<EPI_BF16, 256><<<784 * 6, 256, 0, stream>>>(hw, wq, qkv_b, 6, 768, qkvb, nullptr);

  attn_mfma_kernel<<<4096, 256, 0, stream>>>(qkvb, relb, hw);

  // proj: (100352,256)@(256,256)^T  grid 784*2 = 1568
  gemm_kernel<EPI_PROJ, 256><<<784 * 2, 256, 0, stream>>>(hw, wp, proj_b, 2, 256, x_new, x);

  ln_kernel<<<M_ROWS / 4, 256, 0, stream>>>(x_new, n2w, n2b, y_in);

  // fc1: (100352,256)@(1024,256)^T  grid 784*8 = 6272
  gemm_kernel<EPI_GELU, 256><<<784 * 8, 256, 0, stream>>>(y_in, wf1, fc1_b, 8, 1024, h1, nullptr);

  // fc2: (100352,1024)@(256,1024)^T grid 784*2 = 1568
  gemm_kernel<EPI_ADD, 1024><<<784 * 2, 256, 0, stream>>>(h1, wf2, fc2_b, 2, 256, out, x_new);
}